// Round 3
// baseline (222.150 us; speedup 1.0000x reference)
//
#include <hip/hip_runtime.h>
#include <math.h>

#define NP 30
#define NX 13
#define RPT 4  // rows per thread

typedef float v4f __attribute__((ext_vector_type(4)));

__device__ __forceinline__ void compute_row(
    const float* __restrict__ p,   // 30 params (register array, const-indexed)
    const float* __restrict__ xr,  // 13 state vars
    float CHO, float ins_u, float lQ, float lF,
    float* __restrict__ o)         // 13 outputs
{
    float kmax = p[0],  kmin = p[1],  b    = p[2],  d_   = p[3];
    float kabs = p[4],  f    = p[5],  BW   = p[6],  kp1  = p[7];
    float kp2  = p[8],  kp3  = p[9],  Fsnc = p[10], ke1  = p[11];
    float ke2  = p[12], k1   = p[13], k2   = p[14], Vm0  = p[15];
    float Vmx  = p[16], Km0  = p[17], m1   = p[18], m2   = p[19];
    float m4   = p[20], m30  = p[21], ka1  = p[22], ka2  = p[23];
    float kd   = p[24], Vi   = p[25], p2u  = p[26], Ib   = p[27];
    float ki   = p[28], ksc  = p[29];

    float x0 = xr[0], x1 = xr[1], x2 = xr[2], x3 = xr[3], x4 = xr[4];
    float x5 = xr[5], x6 = xr[6], x7 = xr[7], x8 = xr[8], x9 = xr[9];
    float x10 = xr[10], x11 = xr[11], x12 = xr[12];

    float d       = CHO * 1000.0f;
    float insulin = ins_u * 6000.0f / BW;

    float qsto = x0 + x1;
    float Dbar = lQ + lF;
    bool has_food = Dbar > 0.0f;
    float Dbar_safe = has_food ? Dbar : 1.0f;
    float aa = 2.5f / (1.0f - b) / Dbar_safe;
    float cc = 2.5f / d_ / Dbar_safe;
    float kgut_eating = kmin + (kmax - kmin) * 0.5f *
        (tanhf(aa * (qsto - b * Dbar)) - tanhf(cc * (qsto - d_ * Dbar)) + 2.0f);
    float kgut = has_food ? kgut_eating : kmax;

    o[0] = -kmax * x0 + d;
    o[1] = kmax * x0 - x1 * kgut;
    o[2] = kgut * x1 - kabs * x2;

    float Rat  = f * kabs * x2 / BW;
    float EGPt = kp1 - kp2 * x3 - kp3 * x8;
    float Et   = (x3 > ke2) ? ke1 * (x3 - ke2) : 0.0f;
    o[3] = (fmaxf(EGPt, 0.0f) + Rat - Fsnc - Et - k1 * x3 + k2 * x4) *
           (x3 >= 0.0f ? 1.0f : 0.0f);

    float Vmt  = Vm0 + Vmx * x6;
    float Uidt = Vmt * x4 / (Km0 + x4);
    o[4] = (-Uidt + k1 * x3 - k2 * x4) * (x4 >= 0.0f ? 1.0f : 0.0f);

    o[5] = (-(m2 + m4) * x5 + m1 * x9 + ka1 * x10 + ka2 * x11) *
           (x5 >= 0.0f ? 1.0f : 0.0f);
    float It = x5 / Vi;
    o[6] = -p2u * x6 + p2u * (It - Ib);
    o[7] = -ki * (x7 - It);
    o[8] = -ki * (x8 - x7);
    o[9]  = (-(m1 + m30) * x9 + m2 * x5) * (x9 >= 0.0f ? 1.0f : 0.0f);
    o[10] = (insulin - (ka1 + kd) * x10) * (x10 >= 0.0f ? 1.0f : 0.0f);
    o[11] = (kd * x10 - ka2 * x11) * (x11 >= 0.0f ? 1.0f : 0.0f);
    o[12] = (-ksc * x12 + ksc * x3) * (x12 >= 0.0f ? 1.0f : 0.0f);
}

__global__ __launch_bounds__(256) void t1d_kernel4(
    const float* __restrict__ x,
    const float* __restrict__ params,
    const float* __restrict__ CHO,
    const float* __restrict__ insulin_u,
    const float* __restrict__ last_Qsto,
    const float* __restrict__ last_foodtaken,
    float* __restrict__ out,
    int n)
{
    const long long t  = (long long)blockIdx.x * blockDim.x + threadIdx.x;
    const long long i0 = t * RPT;
    if (i0 >= n) return;

    if (i0 + RPT <= n) {
        // ---- fast path: 4 consecutive rows, everything 16B-aligned float4 ----
        // x slice: 52 floats = 13 f4 (i0*52B, i0%4==0 -> 16B aligned)
        // params slice: 120 floats = 30 f4 (i0*120B -> 16B aligned)
        float xin[RPT * NX];
        {
            const v4f* xs = (const v4f*)(x + i0 * NX);
            v4f* xd = (v4f*)xin;
            #pragma unroll
            for (int k = 0; k < (RPT * NX) / 4; ++k) xd[k] = xs[k];
        }
        float pin[RPT * NP];
        {
            const v4f* ps = (const v4f*)(params + i0 * NP);
            v4f* pd = (v4f*)pin;
            #pragma unroll
            for (int k = 0; k < (RPT * NP) / 4; ++k) pd[k] = ps[k];
        }
        v4f c4 = *(const v4f*)(CHO + i0);
        v4f u4 = *(const v4f*)(insulin_u + i0);
        v4f q4 = *(const v4f*)(last_Qsto + i0);
        v4f f4 = *(const v4f*)(last_foodtaken + i0);

        float ov[RPT * NX];
        #pragma unroll
        for (int r = 0; r < RPT; ++r) {
            compute_row(pin + r * NP, xin + r * NX,
                        c4[r], u4[r], q4[r], f4[r],
                        ov + r * NX);
        }

        // output slice: 52 floats = 13 f4, never re-read -> non-temporal
        v4f* od = (v4f*)(out + i0 * NX);
        const v4f* os = (const v4f*)ov;
        #pragma unroll
        for (int k = 0; k < (RPT * NX) / 4; ++k)
            __builtin_nontemporal_store(os[k], od + k);
    } else {
        // ---- tail: per-row scalar (n not multiple of 4) ----
        for (long long i = i0; i < n; ++i) {
            float pin[NP], xin[NX], ov[NX];
            #pragma unroll
            for (int k = 0; k < NP; ++k) pin[k] = params[i * NP + k];
            #pragma unroll
            for (int k = 0; k < NX; ++k) xin[k] = x[i * NX + k];
            compute_row(pin, xin, CHO[i], insulin_u[i], last_Qsto[i],
                        last_foodtaken[i], ov);
            #pragma unroll
            for (int k = 0; k < NX; ++k) out[i * NX + k] = ov[k];
        }
    }
}

extern "C" void kernel_launch(void* const* d_in, const int* in_sizes, int n_in,
                              void* d_out, int out_size, void* d_ws, size_t ws_size,
                              hipStream_t stream) {
    const float* x    = (const float*)d_in[0];
    const float* par  = (const float*)d_in[1];
    const float* CHO  = (const float*)d_in[2];
    const float* ins  = (const float*)d_in[3];
    const float* lq   = (const float*)d_in[4];
    const float* lf   = (const float*)d_in[5];
    float* out = (float*)d_out;
    int n = in_sizes[2];  // B (CHO length)

    int block = 256;
    long long threads = ((long long)n + RPT - 1) / RPT;
    int grid = (int)((threads + block - 1) / block);
    t1d_kernel4<<<grid, block, 0, stream>>>(x, par, CHO, ins, lq, lf, out, n);
}

// Round 4
// 131.473 us; speedup vs baseline: 1.6897x; 1.6897x over previous
//
#include <hip/hip_runtime.h>
#include <math.h>

#define NP 30
#define NX 13

__global__ __launch_bounds__(256) void t1d_kernel(
    const float* __restrict__ x,
    const float* __restrict__ params,
    const float* __restrict__ CHO,
    const float* __restrict__ insulin_u,
    const float* __restrict__ last_Qsto,
    const float* __restrict__ last_foodtaken,
    float* __restrict__ out,
    int n)
{
    const long long i = (long long)blockIdx.x * blockDim.x + threadIdx.x;
    if (i >= n) return;

    // Load everything into register arrays FIRST (all loads batched in
    // flight before any dependent compute; const-indexed after unroll so
    // they stay in VGPRs, not scratch).
    float pin[NP];
    {
        const float* p = params + i * NP;
        #pragma unroll
        for (int k = 0; k < NP; ++k) pin[k] = p[k];
    }
    float xin[NX];
    {
        const float* xr = x + i * NX;
        #pragma unroll
        for (int k = 0; k < NX; ++k) xin[k] = xr[k];
    }
    float cho = CHO[i];
    float ins = insulin_u[i];
    float lq  = last_Qsto[i];
    float lf  = last_foodtaken[i];

    float kmax = pin[0],  kmin = pin[1],  b    = pin[2],  d_   = pin[3];
    float kabs = pin[4],  f    = pin[5],  BW   = pin[6],  kp1  = pin[7];
    float kp2  = pin[8],  kp3  = pin[9],  Fsnc = pin[10], ke1  = pin[11];
    float ke2  = pin[12], k1   = pin[13], k2   = pin[14], Vm0  = pin[15];
    float Vmx  = pin[16], Km0  = pin[17], m1   = pin[18], m2   = pin[19];
    float m4   = pin[20], m30  = pin[21], ka1  = pin[22], ka2  = pin[23];
    float kd   = pin[24], Vi   = pin[25], p2u  = pin[26], Ib   = pin[27];
    float ki   = pin[28], ksc  = pin[29];

    float x0 = xin[0], x1 = xin[1], x2 = xin[2], x3 = xin[3], x4 = xin[4];
    float x5 = xin[5], x6 = xin[6], x7 = xin[7], x8 = xin[8], x9 = xin[9];
    float x10 = xin[10], x11 = xin[11], x12 = xin[12];

    float d       = cho * 1000.0f;
    float insulin = ins * 6000.0f / BW;

    float qsto = x0 + x1;
    float Dbar = lq + lf;
    bool has_food = Dbar > 0.0f;
    float Dbar_safe = has_food ? Dbar : 1.0f;
    float aa = 2.5f / (1.0f - b) / Dbar_safe;
    float cc = 2.5f / d_ / Dbar_safe;
    float kgut_eating = kmin + (kmax - kmin) * 0.5f *
        (tanhf(aa * (qsto - b * Dbar)) - tanhf(cc * (qsto - d_ * Dbar)) + 2.0f);
    float kgut = has_food ? kgut_eating : kmax;

    float o0 = -kmax * x0 + d;
    float o1 = kmax * x0 - x1 * kgut;
    float o2 = kgut * x1 - kabs * x2;

    float Rat  = f * kabs * x2 / BW;
    float EGPt = kp1 - kp2 * x3 - kp3 * x8;
    float Et   = (x3 > ke2) ? ke1 * (x3 - ke2) : 0.0f;
    float o3 = (fmaxf(EGPt, 0.0f) + Rat - Fsnc - Et - k1 * x3 + k2 * x4) *
               (x3 >= 0.0f ? 1.0f : 0.0f);

    float Vmt  = Vm0 + Vmx * x6;
    float Uidt = Vmt * x4 / (Km0 + x4);
    float o4 = (-Uidt + k1 * x3 - k2 * x4) * (x4 >= 0.0f ? 1.0f : 0.0f);

    float o5 = (-(m2 + m4) * x5 + m1 * x9 + ka1 * x10 + ka2 * x11) *
               (x5 >= 0.0f ? 1.0f : 0.0f);
    float It = x5 / Vi;
    float o6 = -p2u * x6 + p2u * (It - Ib);
    float o7 = -ki * (x7 - It);
    float o8 = -ki * (x8 - x7);
    float o9  = (-(m1 + m30) * x9 + m2 * x5) * (x9 >= 0.0f ? 1.0f : 0.0f);
    float o10 = (insulin - (ka1 + kd) * x10) * (x10 >= 0.0f ? 1.0f : 0.0f);
    float o11 = (kd * x10 - ka2 * x11) * (x11 >= 0.0f ? 1.0f : 0.0f);
    float o12 = (-ksc * x12 + ksc * x3) * (x12 >= 0.0f ? 1.0f : 0.0f);

    // Outputs are never re-read: non-temporal stores keep the 104 MB of
    // writes from evicting replay-resident inputs out of L2/L3.
    float* o = out + i * NX;
    __builtin_nontemporal_store(o0,  o + 0);
    __builtin_nontemporal_store(o1,  o + 1);
    __builtin_nontemporal_store(o2,  o + 2);
    __builtin_nontemporal_store(o3,  o + 3);
    __builtin_nontemporal_store(o4,  o + 4);
    __builtin_nontemporal_store(o5,  o + 5);
    __builtin_nontemporal_store(o6,  o + 6);
    __builtin_nontemporal_store(o7,  o + 7);
    __builtin_nontemporal_store(o8,  o + 8);
    __builtin_nontemporal_store(o9,  o + 9);
    __builtin_nontemporal_store(o10, o + 10);
    __builtin_nontemporal_store(o11, o + 11);
    __builtin_nontemporal_store(o12, o + 12);
}

extern "C" void kernel_launch(void* const* d_in, const int* in_sizes, int n_in,
                              void* d_out, int out_size, void* d_ws, size_t ws_size,
                              hipStream_t stream) {
    const float* x    = (const float*)d_in[0];
    const float* par  = (const float*)d_in[1];
    const float* CHO  = (const float*)d_in[2];
    const float* ins  = (const float*)d_in[3];
    const float* lq   = (const float*)d_in[4];
    const float* lf   = (const float*)d_in[5];
    float* out = (float*)d_out;
    int n = in_sizes[2];  // B (CHO length)

    int block = 256;
    int grid = (int)(((long long)n + block - 1) / block);
    t1d_kernel<<<grid, block, 0, stream>>>(x, par, CHO, ins, lq, lf, out, n);
}

// Round 5
// 93.412 us; speedup vs baseline: 2.3782x; 1.4074x over previous
//
#include <hip/hip_runtime.h>
#include <math.h>

#define NP 30
#define NX 13
#define ROWS 256

typedef float v4f __attribute__((ext_vector_type(4)));

__global__ __launch_bounds__(ROWS) void t1d_kernel(
    const float* __restrict__ x,
    const float* __restrict__ params,
    const float* __restrict__ CHO,
    const float* __restrict__ insulin_u,
    const float* __restrict__ last_Qsto,
    const float* __restrict__ last_foodtaken,
    float* __restrict__ out,
    int n)
{
    // Output staged in LDS, then written back as full-line coalesced
    // non-temporal float4 (16 full 64B lines per wave-instr -> streams to
    // HBM without RMW and without polluting L2/L3, protecting the
    // replay-resident inputs).
    __shared__ float lds_o[ROWS * NX];   // 13312 B

    const int tid = threadIdx.x;
    const long long blockStart = (long long)blockIdx.x * ROWS;
    const long long rem = (long long)n - blockStart;
    if (rem <= 0) return;
    const int nrows = rem < ROWS ? (int)rem : ROWS;

    if (tid < nrows) {
        const long long i = blockStart + tid;

        const float* p = params + i * NP;
        float kmax = p[0],  kmin = p[1],  b    = p[2],  d_   = p[3];
        float kabs = p[4],  f    = p[5],  BW   = p[6],  kp1  = p[7];
        float kp2  = p[8],  kp3  = p[9],  Fsnc = p[10], ke1  = p[11];
        float ke2  = p[12], k1   = p[13], k2   = p[14], Vm0  = p[15];
        float Vmx  = p[16], Km0  = p[17], m1   = p[18], m2   = p[19];
        float m4   = p[20], m30  = p[21], ka1  = p[22], ka2  = p[23];
        float kd   = p[24], Vi   = p[25], p2u  = p[26], Ib   = p[27];
        float ki   = p[28], ksc  = p[29];

        const float* xr = x + i * NX;
        float x0 = xr[0], x1 = xr[1], x2 = xr[2], x3 = xr[3], x4 = xr[4];
        float x5 = xr[5], x6 = xr[6], x7 = xr[7], x8 = xr[8], x9 = xr[9];
        float x10 = xr[10], x11 = xr[11], x12 = xr[12];

        float d       = CHO[i] * 1000.0f;
        float insulin = insulin_u[i] * 6000.0f / BW;

        float qsto = x0 + x1;
        float Dbar = last_Qsto[i] + last_foodtaken[i];
        bool has_food = Dbar > 0.0f;
        float Dbar_safe = has_food ? Dbar : 1.0f;
        float aa = 2.5f / (1.0f - b) / Dbar_safe;
        float cc = 2.5f / d_ / Dbar_safe;
        float kgut_eating = kmin + (kmax - kmin) * 0.5f *
            (tanhf(aa * (qsto - b * Dbar)) - tanhf(cc * (qsto - d_ * Dbar)) + 2.0f);
        float kgut = has_food ? kgut_eating : kmax;

        float* o = lds_o + tid * NX;   // stride-13 scalar LDS writes: gcd(13,32)=1, conflict-free
        o[0] = -kmax * x0 + d;
        o[1] = kmax * x0 - x1 * kgut;
        o[2] = kgut * x1 - kabs * x2;

        float Rat  = f * kabs * x2 / BW;
        float EGPt = kp1 - kp2 * x3 - kp3 * x8;
        float Et   = (x3 > ke2) ? ke1 * (x3 - ke2) : 0.0f;
        o[3] = (fmaxf(EGPt, 0.0f) + Rat - Fsnc - Et - k1 * x3 + k2 * x4) *
               (x3 >= 0.0f ? 1.0f : 0.0f);

        float Vmt  = Vm0 + Vmx * x6;
        float Uidt = Vmt * x4 / (Km0 + x4);
        o[4] = (-Uidt + k1 * x3 - k2 * x4) * (x4 >= 0.0f ? 1.0f : 0.0f);

        o[5] = (-(m2 + m4) * x5 + m1 * x9 + ka1 * x10 + ka2 * x11) *
               (x5 >= 0.0f ? 1.0f : 0.0f);
        float It = x5 / Vi;
        o[6] = -p2u * x6 + p2u * (It - Ib);
        o[7] = -ki * (x7 - It);
        o[8] = -ki * (x8 - x7);
        o[9]  = (-(m1 + m30) * x9 + m2 * x5) * (x9 >= 0.0f ? 1.0f : 0.0f);
        o[10] = (insulin - (ka1 + kd) * x10) * (x10 >= 0.0f ? 1.0f : 0.0f);
        o[11] = (kd * x10 - ka2 * x11) * (x11 >= 0.0f ? 1.0f : 0.0f);
        o[12] = (-ksc * x12 + ksc * x3) * (x12 >= 0.0f ? 1.0f : 0.0f);
    }
    __syncthreads();

    // ---- coalesced non-temporal float4 store of the contiguous chunk ----
    {
        float* dst = out + blockStart * NX;   // 13312*blockIdx B -> 16B aligned
        const int tot = nrows * NX;
        const int nf4 = tot >> 2;
        const v4f* s4 = (const v4f*)lds_o;
        v4f* d4 = (v4f*)dst;
        for (int idx = tid; idx < nf4; idx += ROWS)
            __builtin_nontemporal_store(s4[idx], d4 + idx);
        for (int g = (nf4 << 2) + tid; g < tot; g += ROWS)
            dst[g] = lds_o[g];
    }
}

extern "C" void kernel_launch(void* const* d_in, const int* in_sizes, int n_in,
                              void* d_out, int out_size, void* d_ws, size_t ws_size,
                              hipStream_t stream) {
    const float* x    = (const float*)d_in[0];
    const float* par  = (const float*)d_in[1];
    const float* CHO  = (const float*)d_in[2];
    const float* ins  = (const float*)d_in[3];
    const float* lq   = (const float*)d_in[4];
    const float* lf   = (const float*)d_in[5];
    float* out = (float*)d_out;
    int n = in_sizes[2];  // B (CHO length)

    int grid = (int)(((long long)n + ROWS - 1) / ROWS);
    t1d_kernel<<<grid, ROWS, 0, stream>>>(x, par, CHO, ins, lq, lf, out, n);
}